// Round 2
// baseline (159.717 us; speedup 1.0000x reference)
//
#include <hip/hip_runtime.h>
#include <hip/hip_bf16.h>

// Problem: MultiViewDGT_51745765982512
//   d_in[0] H [N,128] f32, d_in[1] port_w [L] f32, d_in[2] anchor [B] i32,
//   d_in[3] pf_gid [B] i32, d_in[4] port_nodes [L] i32, d_in[5] port_len [G] i32
//   out = concat(V_abs [B,128], V_sgn [B,128]) f32
//
// R8: R6 (2w/group, 8-deep) == R7 (1w/group, 16-deep) -> gather is bound by
// the memory system, not wave schedule: random 256B rows from a 16.7MB table
// thrash the per-XCD 4MiB L2s (every XCD touches the whole table). Fix by
// LOCALITY: store Hb as 8 dim-planes [chunk][node][16dims] (2MiB each) and
// map chunk == blockIdx%8 == XCD. Each XCD's gathers then hit its own
// L2-resident 2MiB plane. per_sample reads the anchor row from fp32 H.

#define DDIM 128

__device__ inline unsigned bf_rne(float x) {
    unsigned u = __float_as_uint(x);
    return (u + 0x7FFFu + ((u >> 16) & 1u)) >> 16;
}

__device__ inline void unpack2(unsigned d, float& lo, float& hi) {
    lo = __uint_as_float(d << 16);
    hi = __uint_as_float(d & 0xFFFF0000u);
}

// Block roles: [0, nconv) convert H->bf16 dim-planes; nconv: used-flags;
// nconv+1: scan.  Plane c (c=0..7) holds dims [16c,16c+16) of every node:
// plane base (uint2s) = c*N*4; row n at n*4; 4 uint2 = 16 bf16 dims.
__global__ __launch_bounds__(1024) void init_kernel(
    const float4* __restrict__ H4, uint2* __restrict__ Hb, int n4, int N,
    const int* __restrict__ plen, int* __restrict__ offs, int G,
    const int* __restrict__ pf_gid, int* __restrict__ used, int B, int nconv) {
    const int t = threadIdx.x;
    const int bb = blockIdx.x;
    if (bb < nconv) {
        const int i = bb * 1024 + t;       // float4 index (= 4 dims)
        if (i < n4) {
            const float4 v = H4[i];
            uint2 o;
            o.x = bf_rne(v.x) | (bf_rne(v.y) << 16);
            o.y = bf_rne(v.z) | (bf_rne(v.w) << 16);
            const int n = i >> 5;          // node (32 float4 per row)
            const int j = i & 31;          // which float4 within the row
            const int cc = j >> 2;         // dim-chunk (16 dims)
            Hb[(size_t)cc * ((size_t)N * 4) + n * 4 + (j & 3)] = o;
        }
        return;
    }
    if (bb == nconv) {
        for (int i = t; i < G; i += 1024) used[i] = 0;
        __syncthreads();
        for (int i = t; i < B; i += 1024) {
            const int g = pf_gid[i];
            if (g >= 0 && g < G) used[g] = 1;
        }
        return;
    }
    // scan role: exclusive prefix sum of plen -> offs
    __shared__ int part[1024];
    const int chunk = (G + 1023) >> 10;
    const int lo = min(t * chunk, G);
    const int hi = min(lo + chunk, G);
    int s = 0;
    for (int i = lo; i < hi; ++i) s += plen[i];
    part[t] = s;
    __syncthreads();
    #pragma unroll
    for (int ofs = 1; ofs < 1024; ofs <<= 1) {
        int v = (t >= ofs) ? part[t - ofs] : 0;
        __syncthreads();
        part[t] += v;
        __syncthreads();
    }
    int run = part[t] - s;
    for (int i = lo; i < hi; ++i) { offs[i] = run; run += plen[i]; }
}

// grid = ceil(G/4) * 8 blocks of 256 (4 waves). Block b: dim-chunk c = b&7
// (-> XCD c via round-robin dispatch), group g = (b>>3)*4 + wave.
// Wave: lane q=lane>>2 takes rows it*16+q, s=lane&3 owns dims
// [16c+4s, 16c+4s+4) as one dwordx2 from the 2MiB plane (L2-resident).
// Combine across q via shfl_xor; lanes 0..3 store 64B of Sabs.
__global__ __launch_bounds__(256) void group_sums(
    const unsigned short* __restrict__ Hp,
    const float* __restrict__ pw, const int* __restrict__ pn,
    const int* __restrict__ plen, const int* __restrict__ offs,
    const int* __restrict__ used,
    float* __restrict__ Sabs, float* __restrict__ Wag,
    float* __restrict__ Wsg, int G, int N) {
    const int b = blockIdx.x;
    const int c = b & 7;
    const int g = (b >> 3) * 4 + (threadIdx.x >> 6);
    if (g >= G) return;
    if (!used[g]) return;           // wave-uniform exit
    const int lane = threadIdx.x & 63;
    const int q = lane >> 2;
    const int s = lane & 3;
    const unsigned short* plane = Hp + (size_t)c * ((size_t)N * 16);

    const int off = offs[g];
    const int len = plen[g];

    float acc0 = 0.f, acc1 = 0.f, acc2 = 0.f, acc3 = 0.f;
    float laWa = 0.f, laWs = 0.f;

    for (int base = 0; base < len; base += 64) {
        float wl = 0.f;
        int nl = 0;   // padding: w=0 contributes nothing; row-0 load harmless
        if (base + lane < len) {
            wl = pw[off + base + lane];
            nl = pn[off + base + lane];
        }
        if (c == 0) { laWa += fabsf(wl); laWs += wl; }

        #pragma unroll
        for (int it = 0; it < 4; ++it) {
            const int src = it * 16 + q;
            const float ww = fabsf(__shfl(wl, src));
            const int row = __shfl(nl, src);
            const uint2 h = *(const uint2*)(plane + (size_t)row * 16 + s * 4);
            float f0, f1, f2, f3;
            unpack2(h.x, f0, f1);
            unpack2(h.y, f2, f3);
            acc0 = fmaf(ww, f0, acc0);
            acc1 = fmaf(ww, f1, acc1);
            acc2 = fmaf(ww, f2, acc2);
            acc3 = fmaf(ww, f3, acc3);
        }
    }

    // combine the 16 q-slots (lane bits 2..5)
    #pragma unroll
    for (int m = 4; m < 64; m <<= 1) {
        acc0 += __shfl_xor(acc0, m);
        acc1 += __shfl_xor(acc1, m);
        acc2 += __shfl_xor(acc2, m);
        acc3 += __shfl_xor(acc3, m);
    }
    if (lane < 4) {
        float4* dst = (float4*)(Sabs + (size_t)g * DDIM + c * 16 + 4 * lane);
        *dst = make_float4(acc0, acc1, acc2, acc3);
    }
    if (c == 0) {
        #pragma unroll
        for (int m = 32; m; m >>= 1) {
            laWa += __shfl_xor(laWa, m);
            laWs += __shfl_xor(laWs, m);
        }
        if (lane == 0) { Wag[g] = laWa; Wsg[g] = laWs; }
    }
}

// One wave per sample: LOO + epilogue. Lane owns dims [2l, 2l+1].
// Anchor row read from fp32 H (coalesced 512B; also more accurate).
__global__ __launch_bounds__(256) void per_sample(
    const float* __restrict__ H,
    const float* __restrict__ pw, const int* __restrict__ pn,
    const int* __restrict__ plen, const int* __restrict__ offs,
    const float* __restrict__ Sabs, const float* __restrict__ Wag,
    const float* __restrict__ Wsg,
    const int* __restrict__ anchor_idx, const int* __restrict__ pf_gid,
    float* __restrict__ out, int B, int G) {
    const int b = blockIdx.x * (blockDim.x >> 6) + (threadIdx.x >> 6);
    const int lane = threadIdx.x & 63;
    if (b >= B) return;

    float2* outA = (float2*)(out + (size_t)b * DDIM);
    float2* outS = (float2*)(out + ((size_t)B + b) * DDIM);

    const int g = pf_gid[b];
    if (!(g >= 0 && g < G)) {
        const float2 z = make_float2(0.f, 0.f);
        outA[lane] = z;
        outS[lane] = z;
        return;
    }

    const int anchor = anchor_idx[b];
    const int off = offs[g];
    const int len = plen[g];

    float selfa = 0.f, selfs = 0.f;
    for (int base = 0; base < len; base += 64) {
        const int jmax = min(64, len - base);
        if (lane < jmax) {
            const float w = pw[off + base + lane];
            const int n = pn[off + base + lane];
            if (n == anchor) { selfa += fabsf(w); selfs += w; }
        }
    }
    #pragma unroll
    for (int m = 32; m; m >>= 1) {
        selfa += __shfl_xor(selfa, m);
        selfs += __shfl_xor(selfs, m);
    }

    const float Wa = Wag[g];
    const float Wsn = Wsg[g];
    const float2 S = ((const float2*)(Sabs + (size_t)g * DDIM))[lane];
    const float2 hv = ((const float2*)(H + (size_t)anchor * DDIM))[lane];

    const float denom = fmaxf(Wa - selfa, 1e-12f);
    float2 v;
    v.x = (S.x - selfa * hv.x) / denom;
    v.y = (S.y - selfa * hv.y) / denom;
    const float scale = (Wsn - selfs) / denom;

    float n2 = v.x * v.x + v.y * v.y;
    #pragma unroll
    for (int m = 32; m; m >>= 1) n2 += __shfl_xor(n2, m);
    const float na = sqrtf(n2);

    const float invA = 1.0f / fmaxf(na, 1e-6f);
    const float ns = fabsf(scale) * na;
    const float sgnscale = (ns > 0.f) ? (scale / fmaxf(ns, 1e-6f)) : scale;

    outA[lane] = make_float2(v.x * invA, v.y * invA);
    outS[lane] = make_float2(v.x * sgnscale, v.y * sgnscale);
}

// ---- fp32 single-kernel fallback (ws too small) ----
__global__ __launch_bounds__(1024) void scan_only(
    const int* __restrict__ len, int* __restrict__ offs, int G) {
    __shared__ int part[1024];
    const int t = threadIdx.x;
    const int chunk = (G + 1023) >> 10;
    const int lo = min(t * chunk, G);
    const int hi = min(lo + chunk, G);
    int s = 0;
    for (int i = lo; i < hi; ++i) s += len[i];
    part[t] = s;
    __syncthreads();
    #pragma unroll
    for (int ofs = 1; ofs < 1024; ofs <<= 1) {
        int v = (t >= ofs) ? part[t - ofs] : 0;
        __syncthreads();
        part[t] += v;
        __syncthreads();
    }
    int run = part[t] - s;
    for (int i = lo; i < hi; ++i) { offs[i] = run; run += len[i]; }
}

__global__ __launch_bounds__(256) void pf_loo_f32(
    const float* __restrict__ H, const float* __restrict__ pw,
    const int* __restrict__ anchor_idx, const int* __restrict__ pf_gid,
    const int* __restrict__ pn, const int* __restrict__ plen,
    const int* __restrict__ offs, float* __restrict__ out, int B, int G) {
    const int b = blockIdx.x * (blockDim.x >> 6) + (threadIdx.x >> 6);
    const int lane = threadIdx.x & 63;
    const int half = lane >> 5;
    const int qlane = lane & 31;
    if (b >= B) return;
    float4* outA = (float4*)(out + (size_t)b * DDIM);
    float4* outS = (float4*)(out + ((size_t)B + b) * DDIM);
    const int gid = pf_gid[b];
    if (!(gid >= 0 && gid < G)) {
        float4 z = make_float4(0.f, 0.f, 0.f, 0.f);
        if (half == 0) { outA[qlane] = z; outS[qlane] = z; }
        return;
    }
    const int anchor = anchor_idx[b];
    const int off = offs[gid];
    const int len = plen[gid];
    float4 acc = make_float4(0.f, 0.f, 0.f, 0.f);
    float laWa = 0.f, laWs = 0.f, laSa = 0.f, laSs = 0.f;
    for (int base = 0; base < len; base += 64) {
        const int jmax = min(64, len - base);
        float wl = 0.f;
        int nl = -1;
        if (lane < jmax) { wl = pw[off + base + lane]; nl = pn[off + base + lane]; }
        const float wla = fabsf(wl);
        laWa += wla; laWs += wl;
        if (nl == anchor) { laSa += wla; laSs += wl; }
        #pragma unroll 8
        for (int jj = 0; jj < 64; jj += 2) {
            const float ww = fabsf(__shfl(wl, jj + half));
            const int row = __shfl(nl, jj + half);
            const float4 h = ((const float4*)(H + (size_t)row * DDIM))[qlane];
            acc.x = fmaf(ww, h.x, acc.x);
            acc.y = fmaf(ww, h.y, acc.y);
            acc.z = fmaf(ww, h.z, acc.z);
            acc.w = fmaf(ww, h.w, acc.w);
        }
    }
    #pragma unroll
    for (int m = 32; m; m >>= 1) {
        laWa += __shfl_xor(laWa, m);
        laWs += __shfl_xor(laWs, m);
        laSa += __shfl_xor(laSa, m);
        laSs += __shfl_xor(laSs, m);
    }
    acc.x += __shfl_xor(acc.x, 32);
    acc.y += __shfl_xor(acc.y, 32);
    acc.z += __shfl_xor(acc.z, 32);
    acc.w += __shfl_xor(acc.w, 32);
    const float denom = fmaxf(laWa - laSa, 1e-12f);
    const float4 hv = ((const float4*)(H + (size_t)anchor * DDIM))[qlane];
    float4 v;
    v.x = (acc.x - laSa * hv.x) / denom;
    v.y = (acc.y - laSa * hv.y) / denom;
    v.z = (acc.z - laSa * hv.z) / denom;
    v.w = (acc.w - laSa * hv.w) / denom;
    const float scale = (laWs - laSs) / denom;
    float n2 = v.x * v.x + v.y * v.y + v.z * v.z + v.w * v.w;
    #pragma unroll
    for (int m = 32; m; m >>= 1) n2 += __shfl_xor(n2, m);
    n2 *= 0.5f;
    const float na = sqrtf(n2);
    const float invA = 1.0f / fmaxf(na, 1e-6f);
    const float ns = fabsf(scale) * na;
    const float sgnscale = (ns > 0.f) ? (scale / fmaxf(ns, 1e-6f)) : scale;
    const float sc = half ? sgnscale : invA;
    float4 res = make_float4(v.x * sc, v.y * sc, v.z * sc, v.w * sc);
    float4* dst = half ? outS : outA;
    dst[qlane] = res;
}

extern "C" void kernel_launch(void* const* d_in, const int* in_sizes, int n_in,
                              void* d_out, int out_size, void* d_ws, size_t ws_size,
                              hipStream_t stream) {
    const float* H      = (const float*)d_in[0];
    const float* pw     = (const float*)d_in[1];
    const int* anchor   = (const int*)d_in[2];
    const int* gid      = (const int*)d_in[3];
    const int* pn       = (const int*)d_in[4];
    const int* plen     = (const int*)d_in[5];
    float* out          = (float*)d_out;

    const int B = in_sizes[2];
    const int G = in_sizes[5];
    const int ND = in_sizes[0];                 // N*128 floats
    const int N  = ND / DDIM;                   // nodes
    const size_t hb_bytes = (size_t)ND * 2;     // bf16 H (8 dim-planes)
    const size_t sabs_bytes = (size_t)G * DDIM * 4;
    const size_t need = hb_bytes + sabs_bytes + (size_t)G * 4 * 4;

    if (ws_size >= need) {
        char* p = (char*)d_ws;
        unsigned short* Hb = (unsigned short*)p;        p += hb_bytes;
        float* Sabs        = (float*)p;                 p += sabs_bytes;
        int* offsp         = (int*)p;                   p += (size_t)G * 4;
        int* usedp         = (int*)p;                   p += (size_t)G * 4;
        float* Wag         = (float*)p;                 p += (size_t)G * 4;
        float* Wsg         = (float*)p;

        const int n4 = ND / 4;
        const int nconv = (n4 + 1023) / 1024;
        init_kernel<<<nconv + 2, 1024, 0, stream>>>(
            (const float4*)H, (uint2*)Hb, n4, N, plen, offsp, G, gid, usedp, B, nconv);

        const int gblocks = ((G + 3) / 4) * 8;
        group_sums<<<gblocks, 256, 0, stream>>>(Hb, pw, pn, plen, offsp, usedp,
                                                Sabs, Wag, Wsg, G, N);

        const int sblocks = (B + 3) / 4;
        per_sample<<<sblocks, 256, 0, stream>>>(H, pw, pn, plen, offsp, Sabs,
                                                Wag, Wsg, anchor, gid, out, B, G);
    } else {
        int* offsp = (int*)d_ws;
        scan_only<<<1, 1024, 0, stream>>>(plen, offsp, G);
        const int blocks = (B + 3) / 4;
        pf_loo_f32<<<blocks, 256, 0, stream>>>(H, pw, anchor, gid, pn, plen,
                                               offsp, out, B, G);
    }
}

// Round 3
// 146.298 us; speedup vs baseline: 1.0917x; 1.0917x over previous
//
#include <hip/hip_runtime.h>
#include <hip/hip_bf16.h>

// Problem: MultiViewDGT_51745765982512
//   d_in[0] H [N,128] f32, d_in[1] port_w [L] f32, d_in[2] anchor [B] i32,
//   d_in[3] pf_gid [B] i32, d_in[4] port_nodes [L] i32, d_in[5] port_len [G] i32
//   out = concat(V_abs [B,128], V_sgn [B,128]) f32
//
// R9: R8 proved XCD-plane locality works (FETCH 72->30MB) but 32B requests
// doubled transaction count and nothing saturated (VALU 36%, occ 56%).
// Fix: 32-dim planes (4 x 4MiB, = L2 size; plane p -> XCDs {p,p+4}), row
// access = one 64B line, gather via async global_load_lds (per-lane global
// addr -> per-wave 4KB LDS tile, no VGPR round-trip), consume via
// ds_read_b64. Full occupancy (VGPR ~40, LDS 16KB/block).

#define DDIM 128

__device__ inline unsigned bf_rne(float x) {
    unsigned u = __float_as_uint(x);
    return (u + 0x7FFFu + ((u >> 16) & 1u)) >> 16;
}

__device__ inline void unpack2(unsigned d, float& lo, float& hi) {
    lo = __uint_as_float(d << 16);
    hi = __uint_as_float(d & 0xFFFF0000u);
}

// Block roles: [0, nconv) convert H->bf16 32-dim planes; nconv: used-flags;
// nconv+1: scan. Plane p (p=0..3) holds dims [32p,32p+32) of every node:
// node n occupies 64B at plane_base + n*64. As uint2 (4 dims): plane p,
// node n, k-th uint2 (k=0..7) at index p*(N*8) + n*8 + k.
__global__ __launch_bounds__(1024) void init_kernel(
    const float4* __restrict__ H4, uint2* __restrict__ Hb, int n4, int N,
    const int* __restrict__ plen, int* __restrict__ offs, int G,
    const int* __restrict__ pf_gid, int* __restrict__ used, int B, int nconv) {
    const int t = threadIdx.x;
    const int bb = blockIdx.x;
    if (bb < nconv) {
        const int i = bb * 1024 + t;       // float4 index (= 4 dims)
        if (i < n4) {
            const float4 v = H4[i];
            uint2 o;
            o.x = bf_rne(v.x) | (bf_rne(v.y) << 16);
            o.y = bf_rne(v.z) | (bf_rne(v.w) << 16);
            const int n = i >> 5;          // node (32 float4 per row)
            const int j = i & 31;          // float4 within the row
            const int p = j >> 3;          // 32-dim plane
            const int k = j & 7;           // uint2 within plane-row
            Hb[(size_t)p * ((size_t)N * 8) + (size_t)n * 8 + k] = o;
        }
        return;
    }
    if (bb == nconv) {
        for (int i = t; i < G; i += 1024) used[i] = 0;
        __syncthreads();
        for (int i = t; i < B; i += 1024) {
            const int g = pf_gid[i];
            if (g >= 0 && g < G) used[g] = 1;
        }
        return;
    }
    // scan role: exclusive prefix sum of plen -> offs
    __shared__ int part[1024];
    const int chunk = (G + 1023) >> 10;
    const int lo = min(t * chunk, G);
    const int hi = min(lo + chunk, G);
    int s = 0;
    for (int i = lo; i < hi; ++i) s += plen[i];
    part[t] = s;
    __syncthreads();
    #pragma unroll
    for (int ofs = 1; ofs < 1024; ofs <<= 1) {
        int v = (t >= ofs) ? part[t - ofs] : 0;
        __syncthreads();
        part[t] += v;
        __syncthreads();
    }
    int run = part[t] - s;
    for (int i = lo; i < hi; ++i) { offs[i] = run; run += plen[i]; }
}

// grid = ceil(G/8)*8 blocks of 256 (4 waves = 4 groups, one plane each).
// Block b: slot = b&7 (-> XCD slot), plane p = slot&3, group-half h = slot>>2,
// wave w handles group g = (b>>3)*8 + h*4 + w on plane p.
// Per 64-line tile: async-gather 64 rows x 64B into a private 4KB LDS tile
// (4 global_load_lds_dwordx4: lane l reads 16B of row shfl(nl, it*16+(l>>2))
// sector l&3), then consume: 8 rounds of ds_read_b64 (lane l: row j*8+(l>>3),
// dims 4*(l&7)), w broadcast via shfl. Combine q-slots via shfl_xor.
__global__ __launch_bounds__(256) void group_sums(
    const unsigned short* __restrict__ Hp,
    const float* __restrict__ pw, const int* __restrict__ pn,
    const int* __restrict__ plen, const int* __restrict__ offs,
    const int* __restrict__ used,
    float* __restrict__ Sabs, float* __restrict__ Wag,
    float* __restrict__ Wsg, int G, int N) {
    const int b = blockIdx.x;
    const int slot = b & 7;
    const int p = slot & 3;
    const int wid = threadIdx.x >> 6;
    const int g = (b >> 3) * 8 + (slot >> 2) * 4 + wid;
    if (g >= G) return;
    if (!used[g]) return;           // wave-uniform exit
    const int lane = threadIdx.x & 63;

    __shared__ unsigned char tile[4][4096];   // per-wave private 64 rows x 64B

    const unsigned short* plane = Hp + (size_t)p * ((size_t)N * 32);
    const int off = offs[g];
    const int len = plen[g];

    const int sg = lane & 3;        // gather sector (16B)
    const int s8 = lane & 7;        // consume: dims [4*s8, 4*s8+4) of plane
    float acc0 = 0.f, acc1 = 0.f, acc2 = 0.f, acc3 = 0.f;
    float laWa = 0.f, laWs = 0.f;

    for (int base = 0; base < len; base += 64) {
        // guard: LDS tile free of pending reads before DMA overwrites it
        asm volatile("s_waitcnt lgkmcnt(0)" ::: "memory");

        float wl = 0.f;
        int nl = 0;   // padding: w=0 contributes nothing; row-0 load harmless
        if (base + lane < len) {
            wl = pw[off + base + lane];
            nl = pn[off + base + lane];
        }
        laWa += fabsf(wl);
        laWs += wl;

        // async gather: 4 x (64 lanes x 16B) = 64 rows x 64B -> LDS
        #pragma unroll
        for (int it = 0; it < 4; ++it) {
            const int row = __shfl(nl, it * 16 + (lane >> 2));
            const unsigned short* gp = plane + (size_t)row * 32 + sg * 8;
            __builtin_amdgcn_global_load_lds(
                (const __attribute__((address_space(1))) unsigned int*)gp,
                (__attribute__((address_space(3))) unsigned int*)&tile[wid][it * 1024],
                16, 0, 0);
        }
        asm volatile("s_waitcnt vmcnt(0)" ::: "memory");

        // consume: 8 rounds, lane l handles row j*8 + (l>>3), 4 dims
        #pragma unroll
        for (int j = 0; j < 8; ++j) {
            const int row = j * 8 + (lane >> 3);
            const float ww = fabsf(__shfl(wl, row));
            const uint2 hv = *(const uint2*)&tile[wid][row * 64 + s8 * 8];
            float f0, f1, f2, f3;
            unpack2(hv.x, f0, f1);
            unpack2(hv.y, f2, f3);
            acc0 = fmaf(ww, f0, acc0);
            acc1 = fmaf(ww, f1, acc1);
            acc2 = fmaf(ww, f2, acc2);
            acc3 = fmaf(ww, f3, acc3);
        }
    }

    // combine the 8 row-slots (lane bits 3..5)
    #pragma unroll
    for (int m = 8; m < 64; m <<= 1) {
        acc0 += __shfl_xor(acc0, m);
        acc1 += __shfl_xor(acc1, m);
        acc2 += __shfl_xor(acc2, m);
        acc3 += __shfl_xor(acc3, m);
    }
    if (lane < 8) {
        float4* dst = (float4*)(Sabs + (size_t)g * DDIM + p * 32 + 4 * lane);
        *dst = make_float4(acc0, acc1, acc2, acc3);
    }
    if (p == 0) {
        #pragma unroll
        for (int m = 32; m; m >>= 1) {
            laWa += __shfl_xor(laWa, m);
            laWs += __shfl_xor(laWs, m);
        }
        if (lane == 0) { Wag[g] = laWa; Wsg[g] = laWs; }
    }
}

// One wave per sample: LOO + epilogue. Lane owns dims [2l, 2l+1].
// Anchor row read from bf16 planes (4x64B lines, same as group layout).
__global__ __launch_bounds__(256) void per_sample(
    const unsigned short* __restrict__ Hp,
    const float* __restrict__ pw, const int* __restrict__ pn,
    const int* __restrict__ plen, const int* __restrict__ offs,
    const float* __restrict__ Sabs, const float* __restrict__ Wag,
    const float* __restrict__ Wsg,
    const int* __restrict__ anchor_idx, const int* __restrict__ pf_gid,
    float* __restrict__ out, int B, int G, int N) {
    const int b = blockIdx.x * (blockDim.x >> 6) + (threadIdx.x >> 6);
    const int lane = threadIdx.x & 63;
    if (b >= B) return;

    float2* outA = (float2*)(out + (size_t)b * DDIM);
    float2* outS = (float2*)(out + ((size_t)B + b) * DDIM);

    const int g = pf_gid[b];
    if (!(g >= 0 && g < G)) {
        const float2 z = make_float2(0.f, 0.f);
        outA[lane] = z;
        outS[lane] = z;
        return;
    }

    const int anchor = anchor_idx[b];
    const int off = offs[g];
    const int len = plen[g];

    float selfa = 0.f, selfs = 0.f;
    for (int base = 0; base < len; base += 64) {
        const int jmax = min(64, len - base);
        if (lane < jmax) {
            const float w = pw[off + base + lane];
            const int n = pn[off + base + lane];
            if (n == anchor) { selfa += fabsf(w); selfs += w; }
        }
    }
    #pragma unroll
    for (int m = 32; m; m >>= 1) {
        selfa += __shfl_xor(selfa, m);
        selfs += __shfl_xor(selfs, m);
    }

    const float Wa = Wag[g];
    const float Wsn = Wsg[g];
    const float2 S = ((const float2*)(Sabs + (size_t)g * DDIM))[lane];
    // dims (2l, 2l+1): plane p = l>>4, within-plane uint = (l&15)
    const unsigned hb = *(const unsigned*)(Hp + (size_t)(lane >> 4) * ((size_t)N * 32)
                                              + (size_t)anchor * 32 + (lane & 15) * 2);
    float h0, h1;
    unpack2(hb, h0, h1);

    const float denom = fmaxf(Wa - selfa, 1e-12f);
    float2 v;
    v.x = (S.x - selfa * h0) / denom;
    v.y = (S.y - selfa * h1) / denom;
    const float scale = (Wsn - selfs) / denom;

    float n2 = v.x * v.x + v.y * v.y;
    #pragma unroll
    for (int m = 32; m; m >>= 1) n2 += __shfl_xor(n2, m);
    const float na = sqrtf(n2);

    const float invA = 1.0f / fmaxf(na, 1e-6f);
    const float ns = fabsf(scale) * na;
    const float sgnscale = (ns > 0.f) ? (scale / fmaxf(ns, 1e-6f)) : scale;

    outA[lane] = make_float2(v.x * invA, v.y * invA);
    outS[lane] = make_float2(v.x * sgnscale, v.y * sgnscale);
}

// ---- fp32 single-kernel fallback (ws too small) ----
__global__ __launch_bounds__(1024) void scan_only(
    const int* __restrict__ len, int* __restrict__ offs, int G) {
    __shared__ int part[1024];
    const int t = threadIdx.x;
    const int chunk = (G + 1023) >> 10;
    const int lo = min(t * chunk, G);
    const int hi = min(lo + chunk, G);
    int s = 0;
    for (int i = lo; i < hi; ++i) s += len[i];
    part[t] = s;
    __syncthreads();
    #pragma unroll
    for (int ofs = 1; ofs < 1024; ofs <<= 1) {
        int v = (t >= ofs) ? part[t - ofs] : 0;
        __syncthreads();
        part[t] += v;
        __syncthreads();
    }
    int run = part[t] - s;
    for (int i = lo; i < hi; ++i) { offs[i] = run; run += len[i]; }
}

__global__ __launch_bounds__(256) void pf_loo_f32(
    const float* __restrict__ H, const float* __restrict__ pw,
    const int* __restrict__ anchor_idx, const int* __restrict__ pf_gid,
    const int* __restrict__ pn, const int* __restrict__ plen,
    const int* __restrict__ offs, float* __restrict__ out, int B, int G) {
    const int b = blockIdx.x * (blockDim.x >> 6) + (threadIdx.x >> 6);
    const int lane = threadIdx.x & 63;
    const int half = lane >> 5;
    const int qlane = lane & 31;
    if (b >= B) return;
    float4* outA = (float4*)(out + (size_t)b * DDIM);
    float4* outS = (float4*)(out + ((size_t)B + b) * DDIM);
    const int gid = pf_gid[b];
    if (!(gid >= 0 && gid < G)) {
        float4 z = make_float4(0.f, 0.f, 0.f, 0.f);
        if (half == 0) { outA[qlane] = z; outS[qlane] = z; }
        return;
    }
    const int anchor = anchor_idx[b];
    const int off = offs[gid];
    const int len = plen[gid];
    float4 acc = make_float4(0.f, 0.f, 0.f, 0.f);
    float laWa = 0.f, laWs = 0.f, laSa = 0.f, laSs = 0.f;
    for (int base = 0; base < len; base += 64) {
        const int jmax = min(64, len - base);
        float wl = 0.f;
        int nl = -1;
        if (lane < jmax) { wl = pw[off + base + lane]; nl = pn[off + base + lane]; }
        const float wla = fabsf(wl);
        laWa += wla; laWs += wl;
        if (nl == anchor) { laSa += wla; laSs += wl; }
        #pragma unroll 8
        for (int jj = 0; jj < 64; jj += 2) {
            const float ww = fabsf(__shfl(wl, jj + half));
            const int row = __shfl(nl, jj + half);
            const float4 h = ((const float4*)(H + (size_t)row * DDIM))[qlane];
            acc.x = fmaf(ww, h.x, acc.x);
            acc.y = fmaf(ww, h.y, acc.y);
            acc.z = fmaf(ww, h.z, acc.z);
            acc.w = fmaf(ww, h.w, acc.w);
        }
    }
    #pragma unroll
    for (int m = 32; m; m >>= 1) {
        laWa += __shfl_xor(laWa, m);
        laWs += __shfl_xor(laWs, m);
        laSa += __shfl_xor(laSa, m);
        laSs += __shfl_xor(laSs, m);
    }
    acc.x += __shfl_xor(acc.x, 32);
    acc.y += __shfl_xor(acc.y, 32);
    acc.z += __shfl_xor(acc.z, 32);
    acc.w += __shfl_xor(acc.w, 32);
    const float denom = fmaxf(laWa - laSa, 1e-12f);
    const float4 hv = ((const float4*)(H + (size_t)anchor * DDIM))[qlane];
    float4 v;
    v.x = (acc.x - laSa * hv.x) / denom;
    v.y = (acc.y - laSa * hv.y) / denom;
    v.z = (acc.z - laSa * hv.z) / denom;
    v.w = (acc.w - laSa * hv.w) / denom;
    const float scale = (laWs - laSs) / denom;
    float n2 = v.x * v.x + v.y * v.y + v.z * v.z + v.w * v.w;
    #pragma unroll
    for (int m = 32; m; m >>= 1) n2 += __shfl_xor(n2, m);
    n2 *= 0.5f;
    const float na = sqrtf(n2);
    const float invA = 1.0f / fmaxf(na, 1e-6f);
    const float ns = fabsf(scale) * na;
    const float sgnscale = (ns > 0.f) ? (scale / fmaxf(ns, 1e-6f)) : scale;
    const float sc = half ? sgnscale : invA;
    float4 res = make_float4(v.x * sc, v.y * sc, v.z * sc, v.w * sc);
    float4* dst = half ? outS : outA;
    dst[qlane] = res;
}

extern "C" void kernel_launch(void* const* d_in, const int* in_sizes, int n_in,
                              void* d_out, int out_size, void* d_ws, size_t ws_size,
                              hipStream_t stream) {
    const float* H      = (const float*)d_in[0];
    const float* pw     = (const float*)d_in[1];
    const int* anchor   = (const int*)d_in[2];
    const int* gid      = (const int*)d_in[3];
    const int* pn       = (const int*)d_in[4];
    const int* plen     = (const int*)d_in[5];
    float* out          = (float*)d_out;

    const int B = in_sizes[2];
    const int G = in_sizes[5];
    const int ND = in_sizes[0];                 // N*128 floats
    const int N  = ND / DDIM;                   // nodes
    const size_t hb_bytes = (size_t)ND * 2;     // bf16 H (4 dim-planes)
    const size_t sabs_bytes = (size_t)G * DDIM * 4;
    const size_t need = hb_bytes + sabs_bytes + (size_t)G * 4 * 4;

    if (ws_size >= need) {
        char* p = (char*)d_ws;
        unsigned short* Hb = (unsigned short*)p;        p += hb_bytes;
        float* Sabs        = (float*)p;                 p += sabs_bytes;
        int* offsp         = (int*)p;                   p += (size_t)G * 4;
        int* usedp         = (int*)p;                   p += (size_t)G * 4;
        float* Wag         = (float*)p;                 p += (size_t)G * 4;
        float* Wsg         = (float*)p;

        const int n4 = ND / 4;
        const int nconv = (n4 + 1023) / 1024;
        init_kernel<<<nconv + 2, 1024, 0, stream>>>(
            (const float4*)H, (uint2*)Hb, n4, N, plen, offsp, G, gid, usedp, B, nconv);

        const int gblocks = ((G + 7) / 8) * 8;
        group_sums<<<gblocks, 256, 0, stream>>>(Hb, pw, pn, plen, offsp, usedp,
                                                Sabs, Wag, Wsg, G, N);

        const int sblocks = (B + 3) / 4;
        per_sample<<<sblocks, 256, 0, stream>>>(Hb, pw, pn, plen, offsp, Sabs,
                                                Wag, Wsg, anchor, gid, out, B, G, N);
    } else {
        int* offsp = (int*)d_ws;
        scan_only<<<1, 1024, 0, stream>>>(plen, offsp, G);
        const int blocks = (B + 3) / 4;
        pf_loo_f32<<<blocks, 256, 0, stream>>>(H, pw, anchor, gid, pn, plen,
                                               offsp, out, B, G);
    }
}